// Round 2
// baseline (303.286 us; speedup 1.0000x reference)
//
#include <hip/hip_runtime.h>

#define P_TERMS 24

typedef _Float16 f16x8 __attribute__((ext_vector_type(8)));
typedef float f32x16 __attribute__((ext_vector_type(16)));

static __device__ __forceinline__ unsigned pk2(float a, float b) {
  unsigned d;
  asm("v_cvt_pkrtz_f16_f32 %0, %1, %2" : "=v"(d) : "v"(a), "v"(b));
  return d;
}
static __device__ __forceinline__ unsigned pkadd(unsigned a, unsigned b) {
  unsigned d;
  asm("v_pk_add_f16 %0, %1, %2" : "=v"(d) : "v"(a), "v"(b));
  return d;
}

// ---------------- K1: c_p = A^p B (sequential, tiny), E[p][m] = C . c_p ----
__global__ __launch_bounds__(256) void s4_powers(
    const float* __restrict__ A, const float* __restrict__ B,
    const float* __restrict__ C, float* __restrict__ E) {
  __shared__ float cp[P_TERMS + 1][64];
  __shared__ float cur[64];
  const int tid = threadIdx.x;
  if (tid < 64) { cur[tid] = B[tid]; cp[0][tid] = B[tid]; }
  __syncthreads();
  const int n = tid >> 2, g = tid & 3;
  for (int p = 1; p <= P_TERMS; ++p) {
    float s = 0.f;
    const int j0 = g * 16;
#pragma unroll
    for (int j = 0; j < 16; ++j) s += A[n * 64 + j0 + j] * cur[j0 + j];
    s += __shfl_xor(s, 1);
    s += __shfl_xor(s, 2);
    __syncthreads();
    if (g == 0) { cur[n] = s; cp[p][n] = s; }
    __syncthreads();
  }
  const int m = tid;  // 0..255
#pragma unroll 1
  for (int p = 0; p <= P_TERMS; ++p) {
    float s = 0.f;
    for (int nn = 0; nn < 64; ++nn) s += C[m * 64 + nn] * cp[p][nn];
    E[p * 256 + m] = s;
  }
}

// ---------------- K2: W[k][m] = sum_p binom(k,p) dt^p E[p][m]; store f16 [m][k]
__global__ __launch_bounds__(512) void s4_wt(
    const float* __restrict__ E, const float* __restrict__ log_dt,
    _Float16* __restrict__ Wtb) {
  __shared__ float Em[P_TERMS + 1];
  const int m = blockIdx.x;
  const int k = threadIdx.x;  // 0..511
  if (k <= P_TERMS) Em[k] = E[k * 256 + m];
  __syncthreads();
  const float dt = __expf(log_dt[0]);
  float coef = 1.f, s = Em[0];
#pragma unroll 1
  for (int p = 1; p <= P_TERMS; ++p) {
    coef *= dt * (float)(k - p + 1) / (float)p;  // zero for p>k, stays zero
    s += coef * Em[p];
  }
  Wtb[m * 512 + k] = (_Float16)s;
}

// ---------------- K3: per-channel Y = dt * (W-rows @ G-cols) + 2 u D -------
// Operand-swapped MFMA: A = W (rows = m, from global/L1), B = G (cols = t,
// built in-register from LDS quads). D rows = m in regs -> float4 stores.
__global__ __launch_bounds__(256, 4) void s4_main(
    const float* __restrict__ x, const _Float16* __restrict__ Wtb,
    const float* __restrict__ Dvec, const float* __restrict__ log_dt,
    float* __restrict__ out) {
  __shared__ float us_pad[1544];  // uf(g) = us_pad[g+4], zero-padded both ends
  __shared__ uint2 QF[1536];      // QF[i] = f16 quad uf(i..i+3)
  __shared__ uint2 QR[1536];      // QR[i] = f16 quad uf(1535-i .. 1532-i)

  const int tid = threadIdx.x;
  const int bid = blockIdx.x;
  const int tt = bid & 7;
  const int ch = bid >> 3;
  const int b = ch >> 8;
  const int d = ch & 255;

  for (int i = tid; i < 1544; i += 256) {
    const int g = i - 516;  // u time index
    us_pad[i] = (g >= 0 && g < 512) ? x[(b * 512 + g) * 256 + d] : 0.f;
  }
  __syncthreads();
  for (int i = tid; i < 1536; i += 256) {
    QF[i] = make_uint2(pk2(us_pad[i + 4], us_pad[i + 5]),
                       pk2(us_pad[i + 6], us_pad[i + 7]));
    QR[i] = make_uint2(pk2(us_pad[1539 - i], us_pad[1538 - i]),
                       pk2(us_pad[1537 - i], us_pad[1536 - i]));
  }
  __syncthreads();

  const int lane = tid & 63;
  const int wid = tid >> 6;
  const int wrow = wid >> 1;  // t sub-tile
  const int wcol = wid & 1;   // m half
  const int r = lane & 31;
  const int hi = lane >> 5;
  const int tbase = tt * 64 + wrow * 32;
  const int mbase = wcol * 128;
  const int t = tbase + r;

  f32x16 acc[4];
#pragma unroll
  for (int mi = 0; mi < 4; ++mi)
#pragma unroll
    for (int e = 0; e < 16; ++e) acc[mi][e] = 0.f;

  int cf = 512 + t + hi * 8;   // fwd quad index: uf(512+t+k0+j)
  int ir = 1023 - t + hi * 8;  // rev quad index: uf(512+t-k0-j)

  for (int kk = 0; kk < 512; kk += 16) {
    const uint2 q0 = QF[cf];
    const uint2 q1 = QF[cf + 4];
    const uint2 s0 = QR[ir];
    const uint2 s1 = QR[ir + 4];
    union { unsigned w[4]; f16x8 v; } gf;
    gf.w[0] = pkadd(q0.x, s0.x);
    gf.w[1] = pkadd(q0.y, s0.y);
    gf.w[2] = pkadd(q1.x, s1.x);
    gf.w[3] = pkadd(q1.y, s1.y);

    const int k0 = kk + hi * 8;
    f16x8 wf[4];
#pragma unroll
    for (int mi = 0; mi < 4; ++mi)
      wf[mi] = *reinterpret_cast<const f16x8*>(
          &Wtb[(mbase + mi * 32 + r) * 512 + k0]);
#pragma unroll
    for (int mi = 0; mi < 4; ++mi)
      acc[mi] =
          __builtin_amdgcn_mfma_f32_32x32x16_f16(wf[mi], gf.v, acc[mi], 0, 0, 0);

    cf += 16;
    ir += 16;
  }

  const float dtv = __expf(log_dt[0]);
  const float uv2 = 2.f * us_pad[516 + t];  // u[b][t][d]
#pragma unroll
  for (int mi = 0; mi < 4; ++mi) {
#pragma unroll
    for (int g = 0; g < 4; ++g) {
      const int m0 = mbase + mi * 32 + 8 * g + 4 * hi;
      const float4 Dq = *reinterpret_cast<const float4*>(&Dvec[m0]);
      float4 o;
      o.x = dtv * acc[mi][4 * g + 0] + uv2 * Dq.x;
      o.y = dtv * acc[mi][4 * g + 1] + uv2 * Dq.y;
      o.z = dtv * acc[mi][4 * g + 2] + uv2 * Dq.z;
      o.w = dtv * acc[mi][4 * g + 3] + uv2 * Dq.w;
      *reinterpret_cast<float4*>(
          &out[(((size_t)b * 512 + t) * 256 + d) * 256 + m0]) = o;
    }
  }
}

extern "C" void kernel_launch(void* const* d_in, const int* in_sizes, int n_in,
                              void* d_out, int out_size, void* d_ws, size_t ws_size,
                              hipStream_t stream) {
  (void)in_sizes; (void)n_in; (void)out_size; (void)ws_size;
  const float* x = (const float*)d_in[0];
  const float* A = (const float*)d_in[1];
  const float* B = (const float*)d_in[2];
  const float* C = (const float*)d_in[3];
  const float* D = (const float*)d_in[4];
  const float* log_dt = (const float*)d_in[5];
  float* out = (float*)d_out;

  float* E = (float*)d_ws;                           // 25*256*4 = 25.6 KB
  _Float16* Wtb = (_Float16*)((char*)d_ws + 32768);  // 256*512*2 = 256 KB

  s4_powers<<<1, 256, 0, stream>>>(A, B, C, E);
  s4_wt<<<256, 512, 0, stream>>>(E, log_dt, Wtb);
  s4_main<<<4096, 256, 0, stream>>>(x, Wtb, D, log_dt, out);
}

// Round 4
// 127.770 us; speedup vs baseline: 2.3737x; 2.3737x over previous
//
#include <hip/hip_runtime.h>

#define P_TERMS 24

typedef _Float16 f16x8 __attribute__((ext_vector_type(8)));
typedef float f32x16 __attribute__((ext_vector_type(16)));

static __device__ __forceinline__ unsigned pk2(float a, float b) {
  unsigned d;
  asm("v_cvt_pkrtz_f16_f32 %0, %1, %2" : "=v"(d) : "v"(a), "v"(b));
  return d;
}
// d.lo = a.lo + b.hi ; d.hi = a.hi + b.lo   (f16x2, swapped src1)
static __device__ __forceinline__ unsigned pkadd_sw(unsigned a, unsigned b) {
  unsigned d;
  asm("v_pk_add_f16 %0, %1, %2 op_sel:[0,1] op_sel_hi:[1,0]"
      : "=v"(d) : "v"(a), "v"(b));
  return d;
}

// ---------------- K1: c_p = A^p B (sequential, tiny), E[p][m] = C . c_p ----
__global__ __launch_bounds__(256) void s4_powers(
    const float* __restrict__ A, const float* __restrict__ B,
    const float* __restrict__ C, float* __restrict__ E) {
  __shared__ float cp[P_TERMS + 1][64];
  __shared__ float cur[64];
  const int tid = threadIdx.x;
  if (tid < 64) { cur[tid] = B[tid]; cp[0][tid] = B[tid]; }
  __syncthreads();
  const int n = tid >> 2, g = tid & 3;
  for (int p = 1; p <= P_TERMS; ++p) {
    float s = 0.f;
    const int j0 = g * 16;
#pragma unroll
    for (int j = 0; j < 16; ++j) s += A[n * 64 + j0 + j] * cur[j0 + j];
    s += __shfl_xor(s, 1);
    s += __shfl_xor(s, 2);
    __syncthreads();
    if (g == 0) { cur[n] = s; cp[p][n] = s; }
    __syncthreads();
  }
  const int m = tid;  // 0..255
#pragma unroll 1
  for (int p = 0; p <= P_TERMS; ++p) {
    float s = 0.f;
    for (int nn = 0; nn < 64; ++nn) s += C[m * 64 + nn] * cp[p][nn];
    E[p * 256 + m] = s;
  }
}

// ------- K2: W[k][m] = sum_p binom(k,p) dt^p E[p][m]; store f16 [k/8][m][8]
__global__ __launch_bounds__(512) void s4_wt(
    const float* __restrict__ E, const float* __restrict__ log_dt,
    _Float16* __restrict__ Wt8) {
  __shared__ float Em[P_TERMS + 1];
  const int m = blockIdx.x;
  const int k = threadIdx.x;  // 0..511
  if (k <= P_TERMS) Em[k] = E[k * 256 + m];
  __syncthreads();
  const float dt = __expf(log_dt[0]);
  float coef = 1.f, s = Em[0];
#pragma unroll 1
  for (int p = 1; p <= P_TERMS; ++p) {
    coef *= dt * (float)(k - p + 1) / (float)p;  // zero for p>k, stays zero
    s += coef * Em[p];
  }
  Wt8[((size_t)(k >> 3) * 256 + m) * 8 + (k & 7)] = (_Float16)s;
}

// ---------------- K3: Y = dt * (G @ W) + 2 u D --------------------------
// A = G (rows t, built from LDS quads w/ in-register reversal), B = W
// ([k/8][m][8] coalesced global). D cols = m in lanes -> 128B store segs.
__global__ __launch_bounds__(256, 2) void s4_main(
    const float* __restrict__ x, const _Float16* __restrict__ Wt8,
    const float* __restrict__ Dvec, const float* __restrict__ log_dt,
    float* __restrict__ out) {
  __shared__ float us_pad[1552];  // uf(g) = us_pad[g+4]; zero-padded
  __shared__ uint4 UF8[1536];     // UF8[i] = f16{uf(i..i+7)}

  const int tid = threadIdx.x;
  const int bid = blockIdx.x;
  const int mhalf = bid & 1;
  const int thalf = (bid >> 1) & 1;
  const int ch = bid >> 2;
  const int b = ch >> 8;
  const int d = ch & 255;

  for (int i = tid; i < 1552; i += 256) {
    const int g = i - 516;  // u time index
    us_pad[i] = (g >= 0 && g < 512) ? x[(b * 512 + g) * 256 + d] : 0.f;
  }
  __syncthreads();
  {
    const int i0 = tid * 6;  // 256*6 = 1536 entries
    float w[14];
#pragma unroll
    for (int j = 0; j < 14; ++j) w[j] = us_pad[i0 + 4 + j];
    unsigned P[13];
#pragma unroll
    for (int j = 0; j < 13; ++j) P[j] = pk2(w[j], w[j + 1]);
#pragma unroll
    for (int e = 0; e < 6; ++e)
      UF8[i0 + e] = make_uint4(P[e], P[e + 2], P[e + 4], P[e + 6]);
  }
  __syncthreads();

  const int lane = tid & 63;
  const int wid = tid >> 6;
  const int r = lane & 31;
  const int hi = lane >> 5;
  const int tbase = thalf * 256 + wid * 64;  // wave covers 64 t
  const int mb = mhalf * 128;                // wave covers 128 m
  const int t0 = tbase + r;

  f32x16 acc[2][4];
#pragma unroll
  for (int ti = 0; ti < 2; ++ti)
#pragma unroll
    for (int mi = 0; mi < 4; ++mi)
#pragma unroll
      for (int e = 0; e < 16; ++e) acc[ti][mi][e] = 0.f;

  int i_f = 512 + t0 + hi * 8;  // fwd window start (k0 = kk + hi*8)
  int i_r = 505 + t0 - hi * 8;  // rev window start
  const _Float16* wbase = Wt8 + ((size_t)(mb + r) << 3) + ((size_t)hi << 11);

  for (int kk = 0; kk < 512; kk += 16) {
    const uint4 F0 = UF8[i_f];
    const uint4 F1 = UF8[i_f + 32];
    const uint4 R0 = UF8[i_r];
    const uint4 R1 = UF8[i_r + 32];
    union { unsigned w[4]; f16x8 v; } g0, g1;
    g0.w[0] = pkadd_sw(F0.x, R0.w);
    g0.w[1] = pkadd_sw(F0.y, R0.z);
    g0.w[2] = pkadd_sw(F0.z, R0.y);
    g0.w[3] = pkadd_sw(F0.w, R0.x);
    g1.w[0] = pkadd_sw(F1.x, R1.w);
    g1.w[1] = pkadd_sw(F1.y, R1.z);
    g1.w[2] = pkadd_sw(F1.z, R1.y);
    g1.w[3] = pkadd_sw(F1.w, R1.x);

    const _Float16* wk = wbase + ((size_t)(kk >> 3) << 11);
    f16x8 wf[4];
#pragma unroll
    for (int mi = 0; mi < 4; ++mi)
      wf[mi] = *reinterpret_cast<const f16x8*>(wk + mi * 256);  // mi*32 m * 8

#pragma unroll
    for (int mi = 0; mi < 4; ++mi) {
      acc[0][mi] =
          __builtin_amdgcn_mfma_f32_32x32x16_f16(g0.v, wf[mi], acc[0][mi], 0, 0, 0);
      acc[1][mi] =
          __builtin_amdgcn_mfma_f32_32x32x16_f16(g1.v, wf[mi], acc[1][mi], 0, 0, 0);
    }
    i_f += 16;
    i_r -= 16;
  }

  const float dtv = __expf(log_dt[0]);
#pragma unroll
  for (int ti = 0; ti < 2; ++ti) {
    const int tb2 = tbase + ti * 32 + 4 * hi;
#pragma unroll
    for (int mi = 0; mi < 4; ++mi) {
      const int m = mb + mi * 32 + r;
      const float Dm = Dvec[m];
#pragma unroll
      for (int reg = 0; reg < 16; ++reg) {
        const int trow = tb2 + (reg & 3) + 8 * (reg >> 2);
        const float uv = us_pad[516 + trow];
        __builtin_nontemporal_store(
            dtv * acc[ti][mi][reg] + 2.f * uv * Dm,
            &out[(((size_t)b * 512 + trow) * 256 + d) * 256 + m]);
      }
    }
  }
}

extern "C" void kernel_launch(void* const* d_in, const int* in_sizes, int n_in,
                              void* d_out, int out_size, void* d_ws, size_t ws_size,
                              hipStream_t stream) {
  (void)in_sizes; (void)n_in; (void)out_size; (void)ws_size;
  const float* x = (const float*)d_in[0];
  const float* A = (const float*)d_in[1];
  const float* B = (const float*)d_in[2];
  const float* C = (const float*)d_in[3];
  const float* D = (const float*)d_in[4];
  const float* log_dt = (const float*)d_in[5];
  float* out = (float*)d_out;

  float* E = (float*)d_ws;                           // 25*256*4 = 25.6 KB
  _Float16* Wt8 = (_Float16*)((char*)d_ws + 32768);  // 512*256*2 = 256 KB

  s4_powers<<<1, 256, 0, stream>>>(A, B, C, E);
  s4_wt<<<256, 512, 0, stream>>>(E, log_dt, Wt8);
  s4_main<<<2048, 256, 0, stream>>>(x, Wt8, D, log_dt, out);
}